// Round 1
// baseline (46.801 us; speedup 1.0000x reference)
//
#include <hip/hip_runtime.h>

// out[k,i,l] = sum_{j<l} w[i,j]*x[k,j] + bias[i]
// B=128, N_h=512, size_in=1024 (fixed by the problem; derived defensively below).
// One 64-lane wave per output row (k,i). Each lane owns 4 consecutive floats
// per 256-element chunk -> float4 coalesced loads/stores. Wave-scan via shfl_up.

#define SIZE_IN 1024
#define N_H 512

__global__ __launch_bounds__(256) void nade_kernel(
    const float* __restrict__ x,     // [B, SIZE_IN]
    const float* __restrict__ w,     // [N_H, SIZE_IN]
    const float* __restrict__ bias,  // [N_H]
    float* __restrict__ out)         // [B, N_H, SIZE_IN]
{
    const int lane = threadIdx.x & 63;
    const int wave = threadIdx.x >> 6;
    const int row  = blockIdx.x * 4 + wave;   // row = k*N_H + i
    const int k = row >> 9;                   // row / N_H
    const int i = row & (N_H - 1);            // row % N_H

    const float* xr = x + (size_t)k * SIZE_IN;
    const float* wr = w + (size_t)i * SIZE_IN;
    float* outr = out + (size_t)row * SIZE_IN;
    const float b = bias[i];

    float carry = 0.0f;
#pragma unroll
    for (int c = 0; c < 4; ++c) {
        const int j0 = c * 256 + lane * 4;
        const float4 xv = *reinterpret_cast<const float4*>(xr + j0);
        const float4 wv = *reinterpret_cast<const float4*>(wr + j0);
        const float t0 = xv.x * wv.x;
        const float t1 = xv.y * wv.y;
        const float t2 = xv.z * wv.z;
        const float t3 = xv.w * wv.w;
        // in-lane inclusive prefix of the 4 products
        const float p0 = t0;
        const float p1 = p0 + t1;
        const float p2 = p1 + t2;
        const float p3 = p2 + t3;
        // wave-wide inclusive scan of per-lane sums (p3)
        float s = p3;
#pragma unroll
        for (int d = 1; d < 64; d <<= 1) {
            const float n = __shfl_up(s, d, 64);
            if (lane >= d) s += n;
        }
        const float excl = carry + (s - p3);  // exclusive prefix at lane's first element
        float4 ov;
        ov.x = excl + b;
        ov.y = excl + p0 + b;
        ov.z = excl + p1 + b;
        ov.w = excl + p2 + b;
        *reinterpret_cast<float4*>(outr + j0) = ov;
        carry += __shfl(s, 63, 64);           // add chunk total
    }
}

extern "C" void kernel_launch(void* const* d_in, const int* in_sizes, int n_in,
                              void* d_out, int out_size, void* d_ws, size_t ws_size,
                              hipStream_t stream) {
    const float* x    = (const float*)d_in[0];
    const float* w    = (const float*)d_in[1];
    const float* bias = (const float*)d_in[2];
    float* out = (float*)d_out;

    const int B = in_sizes[0] / SIZE_IN;      // 128
    const int rows = B * N_H;                  // 65536
    const int blocks = rows / 4;               // 4 waves/block, 1 row/wave

    nade_kernel<<<blocks, 256, 0, stream>>>(x, w, bias, out);
}